// Round 9
// baseline (129.014 us; speedup 1.0000x reference)
//
#include <hip/hip_runtime.h>
#include <math.h>

#define MPTS 8192
#define DIMS 32
#define QB   64      // queries per block
#define NW   16      // waves per block (1024 threads)
#define NEGI -3.4e38f
#define NBLK 256     // grid: 128 qtiles x 2 dirs, 1 block/CU

typedef __bf16 bf16x8 __attribute__((ext_vector_type(8)));
typedef float  f32x4  __attribute__((ext_vector_type(4)));

// Insert v into sorted-DESCENDING top-4 (t0>=t1>=t2>=t3): 1 max + 3 med3.
__device__ __forceinline__ void top4L_insert(float v, float& t0, float& t1, float& t2, float& t3) {
    float n0 = fmaxf(t0, v);
    float n1 = __builtin_amdgcn_fmed3f(v, t0, t1);
    float n2 = __builtin_amdgcn_fmed3f(v, t1, t2);
    float n3 = __builtin_amdgcn_fmed3f(v, t2, t3);
    t0 = n0; t1 = n1; t2 = n2; t3 = n3;
}

// Merge two sorted-desc 4-lists -> sorted-desc top-4 (bitonic half-cleaner + merge).
__device__ __forceinline__ void top4_merge(float u0, float u1, float u2, float u3,
                                           float& t0, float& t1, float& t2, float& t3) {
    float m0 = fmaxf(t0, u3), m1 = fmaxf(t1, u2), m2 = fmaxf(t2, u1), m3 = fmaxf(t3, u0);
    float a = fmaxf(m0, m2), c = fminf(m0, m2);
    float b = fmaxf(m1, m3), d = fminf(m1, m3);
    t0 = fmaxf(a, b); t1 = fminf(a, b); t2 = fmaxf(c, d); t3 = fminf(c, d);
}

__device__ __forceinline__ unsigned short f32_to_bf16_rne(float x) {
    unsigned u = __float_as_uint(x);
    unsigned r = u + 0x7FFFu + ((u >> 16) & 1u);
    return (unsigned short)(r >> 16);
}

// Single-use grid barrier. Release: __threadfence() (gfx950 agent fence = L2 writeback)
// before the agent-scope arrive; acquire: agent-scope atomic spin + __threadfence()
// (L1/L2 invalidate) after. This is the documented cross-XCD visibility protocol.
// Deadlock-free by capacity: 256 blocks, each CU fits 2 (LDS 21KB, VGPR ~56) -> all
// blocks resident from dispatch.
__device__ __forceinline__ void gbar(int* ctr, int target, bool arrive, bool wait) {
    __syncthreads();
    if (threadIdx.x == 0) {
        __threadfence();                                       // release my stores
        if (arrive)
            __hip_atomic_fetch_add(ctr, 1, __ATOMIC_RELEASE, __HIP_MEMORY_SCOPE_AGENT);
        if (wait) {
            while (__hip_atomic_load(ctr, __ATOMIC_ACQUIRE, __HIP_MEMORY_SCOPE_AGENT) < target)
                __builtin_amdgcn_s_sleep(1);
            __threadfence();                                   // acquire: inv stale caches
        }
    }
    __syncthreads();
}

// Megakernel: phase 0 prep (bf16 convert + norms) -> bar -> phase 1 fused 2-pass
// knn+count (body identical to the measured-best round-8 fused_kernel) -> bar ->
// phase 2 epilogue partials (blocks 0..15) -> bar(16) -> phase 3 reduce (block 0).
__global__ __launch_bounds__(1024, 4)
void mega_kernel(const float* __restrict__ P, const float* __restrict__ Q,
                 unsigned short* __restrict__ Phi, unsigned short* __restrict__ Qhi,
                 float* __restrict__ normP, float* __restrict__ normQ,
                 float* __restrict__ nusqP, float* __restrict__ nusqQ,
                 int* __restrict__ countP, int* __restrict__ countQ,
                 int* __restrict__ tots, double* __restrict__ dparts,
                 int* __restrict__ bars, float* __restrict__ out) {
    __shared__ float4 ldsM[NW * QB];     // 16 KB: [wave][query] top-4
    __shared__ int    ldsC[NW * QB];     //  4 KB: [wave][query] counts
    __shared__ float  ldsTau[QB];
    __shared__ double rdQ[8], rdP[8];
    const int tid = threadIdx.x, bid = blockIdx.x;

    // ---------- phase 0: prep (256 active threads per block, 8 elems each) ----------
    if (tid < 256) {
        int t = bid * 256 + tid;                     // 0 .. 65535
        if (t < 2) tots[t] = 0;
        int mat = t >> 15;                           // 0 = P, 1 = Q
        int idx = t & 32767;
        int r = idx >> 2, seg = idx & 3;
        const float* X = mat ? Q : P;
        unsigned short* Xhi = mat ? Qhi : Phi;
        float* nX = mat ? normQ : normP;

        const float* src = X + (size_t)r * DIMS + seg * 8;
        float4 v0 = *(const float4*)(src);
        float4 v1 = *(const float4*)(src + 4);
        float f[8] = {v0.x, v0.y, v0.z, v0.w, v1.x, v1.y, v1.z, v1.w};

        float p = 0.f;
#pragma unroll
        for (int k = 0; k < 8; ++k) p = fmaf(f[k], f[k], p);
        p += __shfl_xor(p, 1);
        p += __shfl_xor(p, 2);                       // seg groups of 4 lane-aligned
        if (seg == 0) nX[r] = -0.5f * p;

        unsigned short h[8];
#pragma unroll
        for (int k = 0; k < 8; ++k) h[k] = f32_to_bf16_rne(f[k]);
        uint4 ph;
        ph.x = (unsigned)h[0] | ((unsigned)h[1] << 16);
        ph.y = (unsigned)h[2] | ((unsigned)h[3] << 16);
        ph.z = (unsigned)h[4] | ((unsigned)h[5] << 16);
        ph.w = (unsigned)h[6] | ((unsigned)h[7] << 16);
        *(uint4*)(Xhi + (size_t)r * DIMS + seg * 8) = ph;
    }
    gbar(&bars[0], NBLK, true, true);

    // ---------- phase 1: fused 2-pass knn+count (round-8 body verbatim) ----------
    {
        const int x = bid & 127, dir = bid >> 7;
        const unsigned short *Yhi, *Xhi2; const float *nY, *nX; float* nusqOut;
        int* cntOut; int* totOut;
        if (dir == 0) { Yhi = Qhi; nY = normQ; Xhi2 = Phi; nX = normP;
                        nusqOut = nusqQ; cntOut = countQ; totOut = &tots[1]; }
        else          { Yhi = Phi; nY = normP; Xhi2 = Qhi; nX = normQ;
                        nusqOut = nusqP; cntOut = countP; totOut = &tots[0]; }
        const int w = tid >> 6, l = tid & 63, q = l & 15, quad = l >> 4;
        const int q0 = x * QB;

        bf16x8 bh[4];
#pragma unroll
        for (int b = 0; b < 4; ++b)
            bh[b] = *(const bf16x8*)(Yhi + (size_t)(q0 + b * 16 + q) * DIMS + quad * 8);

        // pass 1: knn over Y
        float t0[4], t1[4], t2[4], t3[4];
#pragma unroll
        for (int b = 0; b < 4; ++b) t0[b] = t1[b] = t2[b] = t3[b] = NEGI;
        {
            const unsigned short* pH = Yhi + ((size_t)(w * 512) + q) * DIMS + quad * 8;
            const float* pN = nY + w * 512 + quad * 4;
            for (int i = 0; i < 16; ++i) {
                bf16x8 ah0 = *(const bf16x8*)(pH);
                bf16x8 ah1 = *(const bf16x8*)(pH + 16 * DIMS);
                float4 nA0 = *(const float4*)(pN);
                float4 nA1 = *(const float4*)(pN + 16);
                pH += 32 * DIMS; pN += 32;
                f32x4 c0v = {nA0.x, nA0.y, nA0.z, nA0.w};
                f32x4 c1v = {nA1.x, nA1.y, nA1.z, nA1.w};
#pragma unroll
                for (int b = 0; b < 4; ++b) {
                    f32x4 a0 = __builtin_amdgcn_mfma_f32_16x16x32_bf16(ah0, bh[b], c0v, 0, 0, 0);
                    f32x4 a1 = __builtin_amdgcn_mfma_f32_16x16x32_bf16(ah1, bh[b], c1v, 0, 0, 0);
#pragma unroll
                    for (int r = 0; r < 4; ++r) top4L_insert(a0[r], t0[b], t1[b], t2[b], t3[b]);
#pragma unroll
                    for (int r = 0; r < 4; ++r) top4L_insert(a1[r], t0[b], t1[b], t2[b], t3[b]);
                }
            }
        }
        // in-register quad merge
#pragma unroll
        for (int b = 0; b < 4; ++b) {
            float u0 = __shfl_xor(t0[b], 16), u1 = __shfl_xor(t1[b], 16);
            float u2 = __shfl_xor(t2[b], 16), u3 = __shfl_xor(t3[b], 16);
            top4_merge(u0, u1, u2, u3, t0[b], t1[b], t2[b], t3[b]);
            u0 = __shfl_xor(t0[b], 32); u1 = __shfl_xor(t1[b], 32);
            u2 = __shfl_xor(t2[b], 32); u3 = __shfl_xor(t3[b], 32);
            top4_merge(u0, u1, u2, u3, t0[b], t1[b], t2[b], t3[b]);
            if (quad == 0)
                ldsM[w * QB + q + b * 16] = make_float4(t0[b], t1[b], t2[b], t3[b]);
        }
        __syncthreads();
        if (tid < QB) {
            float a0 = NEGI, a1 = NEGI, a2 = NEGI, a3 = NEGI;
#pragma unroll
            for (int u = 0; u < NW; ++u) {
                float4 v = ldsM[u * QB + tid];
                top4L_insert(v.x, a0, a1, a2, a3);
                top4L_insert(v.y, a0, a1, a2, a3);
                top4L_insert(v.z, a0, a1, a2, a3);
                top4L_insert(v.w, a0, a1, a2, a3);
            }
            float nb = -2.0f * nY[q0 + tid];               // |y|^2
            float nu2 = fmaxf(nb - 2.0f * a3, 1e-12f);     // sq-domain nu^2, clamped
            nusqOut[q0 + tid] = nu2;
            ldsTau[tid] = 0.5f * (nb - nu2);               // s-domain threshold
        }
        __syncthreads();
        float tau[4];
#pragma unroll
        for (int b = 0; b < 4; ++b) tau[b] = ldsTau[q + b * 16];

        // pass 2: count over X
        int cnt[4] = {0, 0, 0, 0};
        {
            const unsigned short* pH = Xhi2 + ((size_t)(w * 512) + q) * DIMS + quad * 8;
            const float* pN = nX + w * 512 + quad * 4;
            for (int i = 0; i < 16; ++i) {
                bf16x8 ah0 = *(const bf16x8*)(pH);
                bf16x8 ah1 = *(const bf16x8*)(pH + 16 * DIMS);
                float4 nA0 = *(const float4*)(pN);
                float4 nA1 = *(const float4*)(pN + 16);
                pH += 32 * DIMS; pN += 32;
                f32x4 c0v = {nA0.x, nA0.y, nA0.z, nA0.w};
                f32x4 c1v = {nA1.x, nA1.y, nA1.z, nA1.w};
#pragma unroll
                for (int b = 0; b < 4; ++b) {
                    f32x4 a0 = __builtin_amdgcn_mfma_f32_16x16x32_bf16(ah0, bh[b], c0v, 0, 0, 0);
                    f32x4 a1 = __builtin_amdgcn_mfma_f32_16x16x32_bf16(ah1, bh[b], c1v, 0, 0, 0);
#pragma unroll
                    for (int r = 0; r < 4; ++r) {
                        cnt[b] += (a0[r] >= tau[b]) ? 1 : 0;
                        cnt[b] += (a1[r] >= tau[b]) ? 1 : 0;
                    }
                }
            }
        }
#pragma unroll
        for (int b = 0; b < 4; ++b) {
            int c = cnt[b] + __shfl_xor(cnt[b], 16);
            c += __shfl_xor(c, 32);
            if (quad == 0) ldsC[w * QB + q + b * 16] = c;
        }
        __syncthreads();
        if (tid < QB) {
            int s = 0;
#pragma unroll
            for (int u = 0; u < NW; ++u) s += ldsC[u * QB + tid];
            cntOut[q0 + tid] = s;
            int rsum = s;                                   // block total (wave 0)
            rsum += __shfl_xor(rsum, 1);
            rsum += __shfl_xor(rsum, 2);
            rsum += __shfl_xor(rsum, 4);
            rsum += __shfl_xor(rsum, 8);
            rsum += __shfl_xor(rsum, 16);
            rsum += __shfl_xor(rsum, 32);
            if (tid == 0) atomicAdd(totOut, rsum);          // exact integer sum
        }
    }

    // ---------- bar 2: all arrive; only epilogue blocks wait ----------
    if (bid >= 16) { gbar(&bars[1], NBLK, true, false); return; }
    gbar(&bars[1], NBLK, true, true);

    // ---------- phase 2: epilogue partials (blocks 0..15, 512 active threads) ----------
    {
        const int w2 = tid >> 6, l2 = tid & 63;
        double rQ = 0.0, rP = 0.0;
        if (tid < 512) {
            const int j = bid * 512 + tid;
            const float kq_term = 3.0f / 24576.0f;
            float kpQ = (float)tots[1] + 1e-20f;
            float kpP = (float)tots[0] + 1e-20f;
            {
                float nu = sqrtf(nusqQ[j]);
                float xp = nu * nu; xp *= xp; xp *= xp; xp *= xp; xp *= xp;   // nu^32
                float inv = 1.0f / (xp + 1e-20f);
                float p_den = ((float)countQ[j] / kpQ) * inv;
                p_den = fminf(fmaxf(p_den, 1e-20f), 1e10f);
                float q_den = kq_term * inv;
                q_den = fminf(fmaxf(q_den, 1e-20f), 1e10f);
                rQ = (double)((p_den / q_den) * kq_term);
            }
            {
                float nu = sqrtf(nusqP[j]);
                float xp = nu * nu; xp *= xp; xp *= xp; xp *= xp; xp *= xp;
                float inv = 1.0f / (xp + 1e-20f);
                float p_den = ((float)countP[j] / kpP) * inv;
                p_den = fminf(fmaxf(p_den, 1e-20f), 1e10f);
                float q_den = kq_term * inv;
                q_den = fminf(fmaxf(q_den, 1e-20f), 1e10f);
                rP = (double)((p_den / q_den) * kq_term);
            }
#pragma unroll
            for (int o = 32; o > 0; o >>= 1) { rQ += __shfl_down(rQ, o); rP += __shfl_down(rP, o); }
            if (l2 == 0) { rdQ[w2] = rQ; rdP[w2] = rP; }
        }
        __syncthreads();
        if (tid == 0) {
            double RQ = 0.0, RP = 0.0;
#pragma unroll
            for (int u = 0; u < 8; ++u) { RQ += rdQ[u]; RP += rdP[u]; }
            dparts[bid] = RQ; dparts[16 + bid] = RP;
        }
    }

    // ---------- bar 3 (16 blocks) + phase 3: reduce (block 0) ----------
    if (bid != 0) { gbar(&bars[2], 16, true, false); return; }
    gbar(&bars[2], 16, true, true);
    if (tid == 0) {
        double RQ = 0.0, RP = 0.0;
#pragma unroll
        for (int u = 0; u < 16; ++u) RQ += dparts[u];
#pragma unroll
        for (int u = 0; u < 16; ++u) RP += dparts[16 + u];
        float divP = fmaxf(0.0f, logf((float)RQ));    // alpha=2 -> 1/(alpha-1)=1
        float divQ = fmaxf(0.0f, logf((float)RP));
        out[0] = fmaxf(divP, divQ);
    }
}

extern "C" void kernel_launch(void* const* d_in, const int* in_sizes, int n_in,
                              void* d_out, int out_size, void* d_ws, size_t ws_size,
                              hipStream_t stream) {
    const float* P = (const float*)d_in[0];
    const float* Q = (const float*)d_in[1];
    float* out = (float*)d_out;

    unsigned short* Phi = (unsigned short*)d_ws;
    unsigned short* Qhi = Phi + MPTS * DIMS;
    float* normP = (float*)(Qhi + MPTS * DIMS);
    float* normQ = normP + MPTS;
    float* nusqP = normQ + MPTS;
    float* nusqQ = nusqP + MPTS;
    int* countP  = (int*)(nusqQ + MPTS);
    int* countQ  = countP + MPTS;
    int* tots    = countQ + MPTS;                     // [0]=sum countP, [1]=sum countQ
    double* dparts = (double*)(tots + 4);             // 32 doubles (8B aligned)
    int* bars    = (int*)(dparts + 32);               // 3 single-use barrier counters

    hipMemsetAsync(bars, 0, 4 * sizeof(int), stream);  // counters start poisoned
    mega_kernel<<<NBLK, 1024, 0, stream>>>(P, Q, Phi, Qhi, normP, normQ,
                                           nusqP, nusqQ, countP, countQ,
                                           tots, dparts, bars, out);
}

// Round 10
// 102.211 us; speedup vs baseline: 1.2622x; 1.2622x over previous
//
#include <hip/hip_runtime.h>
#include <math.h>

#define MPTS 8192
#define DIMS 32
#define QB   64      // queries per block
#define NW   16      // waves per block (1024 threads)
#define NEGI -3.4e38f

typedef __bf16 bf16x8 __attribute__((ext_vector_type(8)));
typedef float  f32x4  __attribute__((ext_vector_type(4)));

// Insert v into sorted-DESCENDING top-4 (t0>=t1>=t2>=t3): 1 max + 3 med3.
__device__ __forceinline__ void top4L_insert(float v, float& t0, float& t1, float& t2, float& t3) {
    float n0 = fmaxf(t0, v);
    float n1 = __builtin_amdgcn_fmed3f(v, t0, t1);
    float n2 = __builtin_amdgcn_fmed3f(v, t1, t2);
    float n3 = __builtin_amdgcn_fmed3f(v, t2, t3);
    t0 = n0; t1 = n1; t2 = n2; t3 = n3;
}

// Merge two sorted-desc 4-lists -> sorted-desc top-4 (bitonic half-cleaner + merge, 12 ops).
__device__ __forceinline__ void top4_merge(float u0, float u1, float u2, float u3,
                                           float& t0, float& t1, float& t2, float& t3) {
    float m0 = fmaxf(t0, u3), m1 = fmaxf(t1, u2), m2 = fmaxf(t2, u1), m3 = fmaxf(t3, u0);
    float a = fmaxf(m0, m2), c = fminf(m0, m2);
    float b = fmaxf(m1, m3), d = fminf(m1, m3);
    t0 = fmaxf(a, b); t1 = fminf(a, b); t2 = fmaxf(c, d); t3 = fminf(c, d);
}

__device__ __forceinline__ unsigned short f32_to_bf16_rne(float x) {
    unsigned u = __float_as_uint(x);
    unsigned r = u + 0x7FFFu + ((u >> 16) & 1u);
    return (unsigned short)(r >> 16);
}

// K1: bf16 conversion of P,Q + norms pre-scaled by -0.5 ( -|x|^2/2 ). Also zeroes totals.
__global__ void prep_kernel(const float* __restrict__ P, const float* __restrict__ Q,
                            unsigned short* __restrict__ Phi, unsigned short* __restrict__ Qhi,
                            float* __restrict__ normP, float* __restrict__ normQ,
                            int* __restrict__ tots) {
    if (blockIdx.x == 0 && threadIdx.x < 2) tots[threadIdx.x] = 0;
    int t = blockIdx.x * 256 + threadIdx.x;          // 0 .. 65535
    int mat = t >> 15;                               // 0 = P, 1 = Q
    int idx = t & 32767;
    int r = idx >> 2, seg = idx & 3;                 // 8 elements per thread
    const float* X = mat ? Q : P;
    unsigned short* Xhi = mat ? Qhi : Phi;
    float* nX = mat ? normQ : normP;

    const float* src = X + (size_t)r * DIMS + seg * 8;
    float4 v0 = *(const float4*)(src);
    float4 v1 = *(const float4*)(src + 4);
    float f[8] = {v0.x, v0.y, v0.z, v0.w, v1.x, v1.y, v1.z, v1.w};

    float p = 0.f;
#pragma unroll
    for (int k = 0; k < 8; ++k) p = fmaf(f[k], f[k], p);
    p += __shfl_xor(p, 1);
    p += __shfl_xor(p, 2);      // seg groups of 4 are lane-aligned
    if (seg == 0) nX[r] = -0.5f * p;

    unsigned short h[8];
#pragma unroll
    for (int k = 0; k < 8; ++k) h[k] = f32_to_bf16_rne(f[k]);
    uint4 ph;
    ph.x = (unsigned)h[0] | ((unsigned)h[1] << 16);
    ph.y = (unsigned)h[2] | ((unsigned)h[3] << 16);
    ph.z = (unsigned)h[4] | ((unsigned)h[5] << 16);
    ph.w = (unsigned)h[6] | ((unsigned)h[7] << 16);
    *(uint4*)(Xhi + (size_t)r * DIMS + seg * 8) = ph;
}

// K2: fused 2-pass knn+count (best-measured body across 10 rounds: plain loop, global
// norm loads, compiler scheduling — prefetch/unroll/LDS-norms/filter/grid-barrier all
// measured neutral-negative). grid (128, 2 dirs), 16 waves, 1 block/CU. Block owns 64
// queries; lane holds 4 B-frags (queries q+16b) -> 4 top-4 chains. Wave w scans rows
// [w*512,(w+1)*512): per iter 2 row loads feed 8 MFMAs -> 32 inserts.
// s-domain: s = dot - na/2 (larger == closer). Quad-lists merged in-register via
// shfl_xor(16/32) + bitonic merge; pass 2 counts s >= tau; block totals atomicAdd'd.
__global__ __launch_bounds__(1024, 4)
void fused_kernel(const unsigned short* __restrict__ Phi, const unsigned short* __restrict__ Qhi,
                  const float* __restrict__ normP, const float* __restrict__ normQ,
                  float* __restrict__ nusqP, float* __restrict__ nusqQ,
                  int* __restrict__ countP, int* __restrict__ countQ,
                  int* __restrict__ tots) {
    __shared__ float4 ldsM[NW * QB];     // 16 KB: [wave][query] top-4
    __shared__ int    ldsC[NW * QB];     //  4 KB: [wave][query] counts
    __shared__ float  ldsTau[QB];
    const unsigned short *Yhi, *Xhi; const float *nY, *nX; float* nusqOut;
    int* cntOut; int* totOut;
    if (blockIdx.y == 0) { Yhi = Qhi; nY = normQ; Xhi = Phi; nX = normP;
                           nusqOut = nusqQ; cntOut = countQ; totOut = &tots[1]; } // k_p for div_p
    else                 { Yhi = Phi; nY = normP; Xhi = Qhi; nX = normQ;
                           nusqOut = nusqP; cntOut = countP; totOut = &tots[0]; }
    const int tid = threadIdx.x;
    const int w = tid >> 6, l = tid & 63, q = l & 15, quad = l >> 4;
    const int q0 = blockIdx.x * QB;

    // 4 B-frags: query rows q0 + 16*b + q; k-octet = quad
    bf16x8 bh[4];
#pragma unroll
    for (int b = 0; b < 4; ++b)
        bh[b] = *(const bf16x8*)(Yhi + (size_t)(q0 + b * 16 + q) * DIMS + quad * 8);

    // ---------- pass 1: knn over Y ----------
    float t0[4], t1[4], t2[4], t3[4];
#pragma unroll
    for (int b = 0; b < 4; ++b) t0[b] = t1[b] = t2[b] = t3[b] = NEGI;
    {
        const unsigned short* pH = Yhi + ((size_t)(w * 512) + q) * DIMS + quad * 8;
        const float* pN = nY + w * 512 + quad * 4;
        for (int i = 0; i < 16; ++i) {
            bf16x8 ah0 = *(const bf16x8*)(pH);
            bf16x8 ah1 = *(const bf16x8*)(pH + 16 * DIMS);
            float4 nA0 = *(const float4*)(pN);
            float4 nA1 = *(const float4*)(pN + 16);
            pH += 32 * DIMS; pN += 32;
            f32x4 c0v = {nA0.x, nA0.y, nA0.z, nA0.w};
            f32x4 c1v = {nA1.x, nA1.y, nA1.z, nA1.w};
#pragma unroll
            for (int b = 0; b < 4; ++b) {
                f32x4 a0 = __builtin_amdgcn_mfma_f32_16x16x32_bf16(ah0, bh[b], c0v, 0, 0, 0);
                f32x4 a1 = __builtin_amdgcn_mfma_f32_16x16x32_bf16(ah1, bh[b], c1v, 0, 0, 0);
#pragma unroll
                for (int r = 0; r < 4; ++r) top4L_insert(a0[r], t0[b], t1[b], t2[b], t3[b]);
#pragma unroll
                for (int r = 0; r < 4; ++r) top4L_insert(a1[r], t0[b], t1[b], t2[b], t3[b]);
            }
        }
    }
    // in-register quad merge (lanes q, q+16, q+32, q+48 hold disjoint candidate rows)
#pragma unroll
    for (int b = 0; b < 4; ++b) {
        float u0 = __shfl_xor(t0[b], 16), u1 = __shfl_xor(t1[b], 16);
        float u2 = __shfl_xor(t2[b], 16), u3 = __shfl_xor(t3[b], 16);
        top4_merge(u0, u1, u2, u3, t0[b], t1[b], t2[b], t3[b]);
        u0 = __shfl_xor(t0[b], 32); u1 = __shfl_xor(t1[b], 32);
        u2 = __shfl_xor(t2[b], 32); u3 = __shfl_xor(t3[b], 32);
        top4_merge(u0, u1, u2, u3, t0[b], t1[b], t2[b], t3[b]);
        if (quad == 0)
            ldsM[w * QB + q + b * 16] = make_float4(t0[b], t1[b], t2[b], t3[b]);
    }
    __syncthreads();
    // block merge: 16 wave-lists per query -> exact v4 -> nu, tau
    if (tid < QB) {
        float a0 = NEGI, a1 = NEGI, a2 = NEGI, a3 = NEGI;
#pragma unroll
        for (int u = 0; u < NW; ++u) {
            float4 v = ldsM[u * QB + tid];
            top4L_insert(v.x, a0, a1, a2, a3);
            top4L_insert(v.y, a0, a1, a2, a3);
            top4L_insert(v.z, a0, a1, a2, a3);
            top4L_insert(v.w, a0, a1, a2, a3);
        }
        float nb = -2.0f * nY[q0 + tid];               // |y|^2
        float nu2 = fmaxf(nb - 2.0f * a3, 1e-12f);     // sq-domain nu^2, clamped
        nusqOut[q0 + tid] = nu2;
        ldsTau[tid] = 0.5f * (nb - nu2);               // s-domain threshold
    }
    __syncthreads();
    float tau[4];
#pragma unroll
    for (int b = 0; b < 4; ++b) tau[b] = ldsTau[q + b * 16];

    // ---------- pass 2: count over X ----------
    int cnt[4] = {0, 0, 0, 0};
    {
        const unsigned short* pH = Xhi + ((size_t)(w * 512) + q) * DIMS + quad * 8;
        const float* pN = nX + w * 512 + quad * 4;
        for (int i = 0; i < 16; ++i) {
            bf16x8 ah0 = *(const bf16x8*)(pH);
            bf16x8 ah1 = *(const bf16x8*)(pH + 16 * DIMS);
            float4 nA0 = *(const float4*)(pN);
            float4 nA1 = *(const float4*)(pN + 16);
            pH += 32 * DIMS; pN += 32;
            f32x4 c0v = {nA0.x, nA0.y, nA0.z, nA0.w};
            f32x4 c1v = {nA1.x, nA1.y, nA1.z, nA1.w};
#pragma unroll
            for (int b = 0; b < 4; ++b) {
                f32x4 a0 = __builtin_amdgcn_mfma_f32_16x16x32_bf16(ah0, bh[b], c0v, 0, 0, 0);
                f32x4 a1 = __builtin_amdgcn_mfma_f32_16x16x32_bf16(ah1, bh[b], c1v, 0, 0, 0);
#pragma unroll
                for (int r = 0; r < 4; ++r) {
                    cnt[b] += (a0[r] >= tau[b]) ? 1 : 0;
                    cnt[b] += (a1[r] >= tau[b]) ? 1 : 0;
                }
            }
        }
    }
    // quad reduce in-register, then [wave][query] LDS
#pragma unroll
    for (int b = 0; b < 4; ++b) {
        int c = cnt[b] + __shfl_xor(cnt[b], 16);
        c += __shfl_xor(c, 32);
        if (quad == 0) ldsC[w * QB + q + b * 16] = c;
    }
    __syncthreads();
    if (tid < QB) {
        int s = 0;
#pragma unroll
        for (int u = 0; u < NW; ++u) s += ldsC[u * QB + tid];
        cntOut[q0 + tid] = s;
        int rsum = s;                                   // block total (wave 0)
        rsum += __shfl_xor(rsum, 1);
        rsum += __shfl_xor(rsum, 2);
        rsum += __shfl_xor(rsum, 4);
        rsum += __shfl_xor(rsum, 8);
        rsum += __shfl_xor(rsum, 16);
        rsum += __shfl_xor(rsum, 32);
        if (tid == 0) atomicAdd(totOut, rsum);          // exact integer sum
    }
}

// K3a: epilogue partials, 16 blocks x 512 thr (one j per thread). Per-block double
// partial sums are deterministic (fixed shuffle-tree order); written to dparts.
__global__ __launch_bounds__(512)
void final_partial(const int* __restrict__ countP, const int* __restrict__ countQ,
                   const float* __restrict__ nusqP, const float* __restrict__ nusqQ,
                   const int* __restrict__ tots, double* __restrict__ dparts) {
    __shared__ double rdQ[8], rdP[8];
    const int tid = threadIdx.x, b = blockIdx.x;
    const int w = tid >> 6, l = tid & 63;
    const int j = b * 512 + tid;

    const float kq_term = 3.0f / 24576.0f;
    float kpQ = (float)tots[1] + 1e-20f;
    float kpP = (float)tots[0] + 1e-20f;
    double rQ, rP;
    {
        float nu = sqrtf(nusqQ[j]);
        float x = nu * nu; x *= x; x *= x; x *= x; x *= x;   // nu^32
        float inv = 1.0f / (x + 1e-20f);
        float p_den = ((float)countQ[j] / kpQ) * inv;
        p_den = fminf(fmaxf(p_den, 1e-20f), 1e10f);
        float q_den = kq_term * inv;
        q_den = fminf(fmaxf(q_den, 1e-20f), 1e10f);
        rQ = (double)((p_den / q_den) * kq_term);
    }
    {
        float nu = sqrtf(nusqP[j]);
        float x = nu * nu; x *= x; x *= x; x *= x; x *= x;
        float inv = 1.0f / (x + 1e-20f);
        float p_den = ((float)countP[j] / kpP) * inv;
        p_den = fminf(fmaxf(p_den, 1e-20f), 1e10f);
        float q_den = kq_term * inv;
        q_den = fminf(fmaxf(q_den, 1e-20f), 1e10f);
        rP = (double)((p_den / q_den) * kq_term);
    }
#pragma unroll
    for (int o = 32; o > 0; o >>= 1) { rQ += __shfl_down(rQ, o); rP += __shfl_down(rP, o); }
    if (l == 0) { rdQ[w] = rQ; rdP[w] = rP; }
    __syncthreads();
    if (tid == 0) {
        double RQ = 0.0, RP = 0.0;
#pragma unroll
        for (int u = 0; u < 8; ++u) { RQ += rdQ[u]; RP += rdP[u]; }
        dparts[b] = RQ; dparts[16 + b] = RP;
    }
}

// K3b: tiny reduce, fixed summation order.
__global__ void final_reduce(const double* __restrict__ dparts, float* __restrict__ out) {
    if (threadIdx.x == 0) {
        double RQ = 0.0, RP = 0.0;
#pragma unroll
        for (int u = 0; u < 16; ++u) RQ += dparts[u];
#pragma unroll
        for (int u = 0; u < 16; ++u) RP += dparts[16 + u];
        float divP = fmaxf(0.0f, logf((float)RQ));    // alpha=2 -> 1/(alpha-1)=1
        float divQ = fmaxf(0.0f, logf((float)RP));
        out[0] = fmaxf(divP, divQ);
    }
}

extern "C" void kernel_launch(void* const* d_in, const int* in_sizes, int n_in,
                              void* d_out, int out_size, void* d_ws, size_t ws_size,
                              hipStream_t stream) {
    const float* P = (const float*)d_in[0];
    const float* Q = (const float*)d_in[1];
    float* out = (float*)d_out;

    unsigned short* Phi = (unsigned short*)d_ws;
    unsigned short* Qhi = Phi + MPTS * DIMS;
    float* normP = (float*)(Qhi + MPTS * DIMS);
    float* normQ = normP + MPTS;
    float* nusqP = normQ + MPTS;
    float* nusqQ = nusqP + MPTS;
    int* countP  = (int*)(nusqQ + MPTS);
    int* countQ  = countP + MPTS;
    int* tots    = countQ + MPTS;                     // [0]=sum countP, [1]=sum countQ
    double* dparts = (double*)(tots + 2);             // 32 doubles (8B aligned)

    prep_kernel<<<256, 256, 0, stream>>>(P, Q, Phi, Qhi, normP, normQ, tots);
    fused_kernel<<<dim3(MPTS / QB, 2), 1024, 0, stream>>>(Phi, Qhi, normP, normQ,
                                                          nusqP, nusqQ, countP, countQ, tots);
    final_partial<<<16, 512, 0, stream>>>(countP, countQ, nusqP, nusqQ, tots, dparts);
    final_reduce<<<1, 64, 0, stream>>>(dparts, out);
}